// Round 9
// baseline (259.874 us; speedup 1.0000x reference)
//
#include <hip/hip_runtime.h>
#include <math.h>

#define N_    8
#define C_    256
#define H_    64
#define W_    64
#define HW    4096
#define OUT_  256
#define HEADS 8
#define HD    32
#define K2    9
#define OFFCH 144   // HEADS*K2*2
#define AWCH  72    // HEADS*K2
#define COP   224   // padded conv output channels (216 used)
#define KTOT  2304  // 9 taps * 256 c

typedef __bf16 bf16x8 __attribute__((ext_vector_type(8)));
typedef __bf16 bf16x4 __attribute__((ext_vector_type(4)));
typedef float  f32x4  __attribute__((ext_vector_type(4)));

// ---------------------------------------------------------------------------
// pack_x: fp32 NCHW -> bf16 NHWC  (xp[n][y][x][c]), LDS 64x64 tile transpose.
// ---------------------------------------------------------------------------
__global__ __launch_bounds__(256) void pack_x_kernel(
    const float* __restrict__ x, __bf16* __restrict__ xp)
{
  const int c0 = blockIdx.x << 6;
  const int y  = blockIdx.y;
  const int n  = blockIdx.z;
  const int tid = threadIdx.x;
  __shared__ float tile[64][65];

  const int tx = tid & 63, tg = tid >> 6;
#pragma unroll
  for (int i = 0; i < 16; ++i) {
    int cl = tg + (i << 2);
    tile[cl][tx] = x[((size_t)(n * C_ + c0 + cl) * H_ + y) * W_ + tx];
  }
  __syncthreads();
#pragma unroll
  for (int i = 0; i < 16; ++i) {
    int xl = tg + (i << 2);
    xp[((size_t)(n * HW) + y * W_ + xl) * C_ + c0 + tx] = (__bf16)tile[tx][xl];
  }
}

// ---------------------------------------------------------------------------
// pack_w: conv weights -> bf16 Wp[224][tap][c] (tap-major K), + bias pack.
// ---------------------------------------------------------------------------
__global__ __launch_bounds__(256) void pack_w_kernel(
    const float* __restrict__ off_w, const float* __restrict__ off_b,
    const float* __restrict__ attn_w, const float* __restrict__ attn_b,
    __bf16* __restrict__ Wp, float* __restrict__ biasp)
{
  const int co = blockIdx.x;
  const int c  = threadIdx.x;
  const float* base = nullptr;
  if (co < OFFCH)      base = off_w  + ((size_t)co * C_ + c) * 9;
  else if (co < 216)   base = attn_w + ((size_t)(co - OFFCH) * C_ + c) * 9;
#pragma unroll
  for (int t = 0; t < 9; ++t) {
    float w = base ? base[t] : 0.f;
    Wp[(size_t)co * KTOT + t * C_ + c] = (__bf16)w;
  }
  if (c == 0) {
    float b = 0.f;
    if (co < OFFCH) b = off_b[co];
    else if (co < 216) b = attn_b[co - OFFCH];
    biasp[co] = b;
  }
}

// 256x256 fp32 -> bf16 row-major
__global__ __launch_bounds__(256) void pack_mat_kernel(
    const float* __restrict__ Wsrc, __bf16* __restrict__ Wdst)
{
  const int i = blockIdx.x * 256 + threadIdx.x;
  Wdst[i] = (__bf16)Wsrc[i];
}

// ---------------------------------------------------------------------------
// conv_mfma: implicit-GEMM 3x3 conv via 16x16x32 bf16 MFMA.
// R9: 64-spatial x 112-co tile -> grid 1024 blocks (4 blocks/CU, 16 waves/CU);
// B double-buffered with T14 split staging (load tap t+1 before the MFMA
// cluster of tap t, ds_write after; 2 short-lived uint4/thread, no spill).
// ---------------------------------------------------------------------------
__global__ __launch_bounds__(256) void conv_mfma_kernel(
    const __bf16* __restrict__ xp, const __bf16* __restrict__ Wp,
    const float* __restrict__ biasp, __bf16* __restrict__ P)
{
  const int y0 = blockIdx.x;          // image row (64 spatial outputs)
  const int bn = blockIdx.y;          // co half (0:0..111, 1:112..223)
  const int n  = blockIdx.z;
  const int tid = threadIdx.x;

  __shared__ __align__(16) __bf16 Asl[3][66][40];    // 15.84 KB (y0-1..y0+1)
  __shared__ __align__(16) __bf16 Bsl[2][112][40];   // 17.92 KB (dbuf taps)

  const int lw = tid & 63, wv = tid >> 6;
  const int xb = wv << 4;             // wave's 16 x-positions
  const int lr = lw & 15, lg = lw >> 4;

  f32x4 acc[7];
#pragma unroll
  for (int nt = 0; nt < 7; ++nt) acc[nt] = (f32x4){0.f, 0.f, 0.f, 0.f};

  uint4 breg[2];

  // ---- prologue: zero halo columns x=-1 and x=64 (3 rows x 2 cols x 4 cg) --
  if (tid < 24) {
    int r = tid >> 3, rem = tid & 7;
    int xe = (rem >> 2) ? 65 : 0, cg = rem & 3;
    *(uint4*)&Asl[r][xe][cg << 3] = make_uint4(0u, 0u, 0u, 0u);
  }

  for (int ci = 0; ci < 8; ++ci) {
    const int c0 = ci << 5;
    __syncthreads();                   // prev slice's LDS reads done

    // ---- stage A: 3 rows x 64 x x 32 c = 768 chunks, 3 per thread ----
#pragma unroll
    for (int it = 0; it < 3; ++it) {
      int i  = tid + (it << 8);
      int cg = i & 3, xx = (i >> 2) & 63, r = i >> 8;
      int y = y0 - 1 + r;
      uint4 v = make_uint4(0u, 0u, 0u, 0u);
      if ((unsigned)y < (unsigned)H_)
        v = *(const uint4*)&xp[(((size_t)n * HW) + y * W_ + xx) * C_ + c0 + (cg << 3)];
      *(uint4*)&Asl[r][xx + 1][cg << 3] = v;
    }

    // ---- stage B tap 0 into buf 0 ----
#pragma unroll
    for (int it = 0; it < 2; ++it) {
      int sub = (it << 8) + tid;
      if (sub < 448) {
        int co = sub >> 2, cg = sub & 3;
        breg[it] = *(const uint4*)&Wp[(size_t)(bn * 112 + co) * KTOT +
                                      0 * C_ + c0 + (cg << 3)];
      }
    }
#pragma unroll
    for (int it = 0; it < 2; ++it) {
      int sub = (it << 8) + tid;
      if (sub < 448) {
        int co = sub >> 2, cg = sub & 3;
        *(uint4*)&Bsl[0][co][cg << 3] = breg[it];
      }
    }
    __syncthreads();                   // A + B0 ready

#pragma unroll
    for (int t = 0; t < 9; ++t) {
      // issue next tap's loads BEFORE the MFMA cluster (latency hides under it)
      if (t < 8) {
#pragma unroll
        for (int it = 0; it < 2; ++it) {
          int sub = (it << 8) + tid;
          if (sub < 448) {
            int co = sub >> 2, cg = sub & 3;
            breg[it] = *(const uint4*)&Wp[(size_t)(bn * 112 + co) * KTOT +
                                          (t + 1) * C_ + c0 + (cg << 3)];
          }
        }
      }

      // ---- 7 MFMAs for tap t (reads buf t&1) ----
      bf16x8 a = *(const bf16x8*)&Asl[t / 3][xb + lr + (t % 3)][lg << 3];
      __builtin_amdgcn_s_setprio(1);
#pragma unroll
      for (int nt = 0; nt < 7; ++nt) {
        bf16x8 b = *(const bf16x8*)&Bsl[t & 1][(nt << 4) + lr][lg << 3];
        acc[nt] = __builtin_amdgcn_mfma_f32_16x16x32_bf16(a, b, acc[nt], 0, 0, 0);
      }
      __builtin_amdgcn_s_setprio(0);

      // write next tap into the other buffer (no race: different buffer)
      if (t < 8) {
#pragma unroll
        for (int it = 0; it < 2; ++it) {
          int sub = (it << 8) + tid;
          if (sub < 448) {
            int co = sub >> 2, cg = sub & 3;
            *(uint4*)&Bsl[(t + 1) & 1][co][cg << 3] = breg[it];
          }
        }
      }
      __syncthreads();                 // next buf visible; tap-t reads done
    }
  }

  // ---- epilogue: bias (+ sigmoid for co>=144), store bf16 P[n][s][co] ----
#pragma unroll
  for (int nt = 0; nt < 7; ++nt) {
    const int co = bn * 112 + (nt << 4) + lr;
    const float bias = biasp[co];
#pragma unroll
    for (int reg = 0; reg < 4; ++reg) {
      const int xo = xb + (lg << 2) + reg;
      float v = acc[nt][reg] + bias;
      if (co >= OFFCH) v = 1.f / (1.f + expf(-v));
      P[((size_t)n * HW + y0 * W_ + xo) * COP + co] = (__bf16)v;
    }
  }
}

// ---------------------------------------------------------------------------
// gemm256: D[n][s][co] = sum_c A[n][s][c]*Wb[co][c]
// MODE 0: store bf16 NHWC (vproj -> vtb). MODE 1: store fp32 NCHW (wo -> out).
// ---------------------------------------------------------------------------
template <int MODE>
__global__ __launch_bounds__(256) void gemm256_kernel(
    const __bf16* __restrict__ A, const __bf16* __restrict__ Wb,
    __bf16* __restrict__ out_b, float* __restrict__ out_f)
{
  const int st = blockIdx.x;
  const int bn = blockIdx.y;
  const int n  = blockIdx.z;
  const int s0 = st << 7;
  const int tid = threadIdx.x;

  __shared__ __bf16 Asl[128][40];
  __shared__ __bf16 Bsl[128][40];

  const int lw = tid & 63, wv = tid >> 6;
  const int lr = lw & 15, lg = lw >> 4;
  const int sm_base = wv << 5;

  f32x4 acc[2][8];
#pragma unroll
  for (int m = 0; m < 2; ++m)
#pragma unroll
    for (int nt = 0; nt < 8; ++nt) acc[m][nt] = (f32x4){0.f, 0.f, 0.f, 0.f};

  for (int c0 = 0; c0 < 256; c0 += 32) {
    __syncthreads();
#pragma unroll
    for (int it = 0; it < 2; ++it) {
      int i = tid + (it << 8);
      int cg = i & 3, r = i >> 2;
      *(uint4*)&Asl[r][cg << 3] =
          *(const uint4*)&A[((size_t)n * HW + s0 + r) * 256 + c0 + (cg << 3)];
    }
#pragma unroll
    for (int it = 0; it < 2; ++it) {
      int i = tid + (it << 8);
      int cg = i & 3, r = i >> 2;
      *(uint4*)&Bsl[r][cg << 3] =
          *(const uint4*)&Wb[(size_t)((bn << 7) + r) * 256 + c0 + (cg << 3)];
    }
    __syncthreads();

    bf16x8 a0 = *(const bf16x8*)&Asl[sm_base + lr][lg << 3];
    bf16x8 a1 = *(const bf16x8*)&Asl[sm_base + 16 + lr][lg << 3];
#pragma unroll
    for (int nt = 0; nt < 8; ++nt) {
      bf16x8 b = *(const bf16x8*)&Bsl[(nt << 4) + lr][lg << 3];
      acc[0][nt] = __builtin_amdgcn_mfma_f32_16x16x32_bf16(a0, b, acc[0][nt], 0, 0, 0);
      acc[1][nt] = __builtin_amdgcn_mfma_f32_16x16x32_bf16(a1, b, acc[1][nt], 0, 0, 0);
    }
  }

#pragma unroll
  for (int m = 0; m < 2; ++m) {
#pragma unroll
    for (int nt = 0; nt < 8; ++nt) {
      const int co = (bn << 7) + (nt << 4) + lr;
      if (MODE == 0) {
#pragma unroll
        for (int reg = 0; reg < 4; ++reg) {
          const int sm = sm_base + (m << 4) + (lg << 2) + reg;
          out_b[((size_t)n * HW + s0 + sm) * 256 + co] = (__bf16)acc[m][nt][reg];
        }
      } else {
        const int sm = sm_base + (m << 4) + (lg << 2);
        float4 v4 = make_float4(acc[m][nt][0], acc[m][nt][1],
                                acc[m][nt][2], acc[m][nt][3]);
        *(float4*)&out_f[((size_t)(n * 256 + co)) * HW + s0 + sm] = v4;
      }
    }
  }
}

// ---------------------------------------------------------------------------
// Deformable sampling, channel-split: 8 lanes per (n,h,s), each owns 4 ch.
// ---------------------------------------------------------------------------
__global__ __launch_bounds__(256) void sample_kernel(
    const __bf16* __restrict__ vtb, const __bf16* __restrict__ P,
    __bf16* __restrict__ comb)
{
  const int gid = blockIdx.x * 256 + threadIdx.x;
  const int cg  = gid & 7;
  const int q   = gid >> 3;
  const int s = q & (HW - 1);
  const int h = (q >> 12) & (HEADS - 1);
  const int n = q >> 15;
  const int yq = s >> 6, xq = s & 63;

  float a0 = 0.f, a1 = 0.f, a2 = 0.f, a3 = 0.f;

  const __bf16* prow  = P + ((size_t)n * HW + s) * COP;
  const __bf16* vbase = vtb + ((size_t)n * HW) * OUT_ + h * HD + (cg << 2);

#pragma unroll
  for (int k = 0; k < K2; ++k) {
    const float offx = (float)prow[18 * h + 2 * k];
    const float offy = (float)prow[18 * h + 2 * k + 1];
    const float a    = (float)prow[OFFCH + 9 * h + k];

    const float xpf = (float)xq + offx * (63.f / 64.f);
    const float ypf = (float)yq + offy * (63.f / 64.f);
    const float fx0 = floorf(xpf), fy0 = floorf(ypf);
    const int x0 = (int)fx0, y0 = (int)fy0;
    const float wx1 = xpf - fx0, wx0 = 1.f - wx1;
    const float wy1 = ypf - fy0, wy0 = 1.f - wy1;

#pragma unroll
    for (int cy = 0; cy < 2; ++cy) {
      const int yi = y0 + cy;
      if ((unsigned)yi >= (unsigned)H_) continue;
      const float wy = cy ? wy1 : wy0;
#pragma unroll
      for (int cx = 0; cx < 2; ++cx) {
        const int xi = x0 + cx;
        if ((unsigned)xi >= (unsigned)W_) continue;
        const float cw = a * wy * (cx ? wx1 : wx0);
        bf16x4 v = *(const bf16x4*)(vbase + (size_t)(yi * W_ + xi) * OUT_);
        a0 = fmaf(cw, (float)v[0], a0);
        a1 = fmaf(cw, (float)v[1], a1);
        a2 = fmaf(cw, (float)v[2], a2);
        a3 = fmaf(cw, (float)v[3], a3);
      }
    }
  }

  bf16x4 r;
  r[0] = (__bf16)a0; r[1] = (__bf16)a1; r[2] = (__bf16)a2; r[3] = (__bf16)a3;
  *(bf16x4*)&comb[((size_t)n * HW + s) * OUT_ + h * HD + (cg << 2)] = r;
}

// ---------------------------------------------------------------------------
extern "C" void kernel_launch(void* const* d_in, const int* in_sizes, int n_in,
                              void* d_out, int out_size, void* d_ws,
                              size_t ws_size, hipStream_t stream)
{
  const float* x      = (const float*)d_in[0];
  // d_in[1] = Wq, d_in[2] = Wk : dead code (q,k unused in reference)
  const float* Wv     = (const float*)d_in[3];
  const float* off_w  = (const float*)d_in[4];
  const float* off_b  = (const float*)d_in[5];
  const float* attn_w = (const float*)d_in[6];
  const float* attn_b = (const float*)d_in[7];
  const float* Wo     = (const float*)d_in[8];
  float* out = (float*)d_out;

  __bf16* vtb   = (__bf16*)d_ws;                         // 16.78 MB
  __bf16* xp    = vtb + (size_t)N_ * HW * OUT_;          // 16.78 MB
  __bf16* comb  = xp + (size_t)N_ * HW * C_;             // 16.78 MB
  __bf16* P     = comb + (size_t)N_ * HW * OUT_;         // 14.68 MB
  __bf16* Wp    = P + (size_t)N_ * HW * COP;             //  1.03 MB
  __bf16* Wvb   = Wp + (size_t)COP * KTOT;               //  128 KB
  __bf16* Wob   = Wvb + (size_t)OUT_ * C_;               //  128 KB
  float*  biasp = (float*)(Wob + (size_t)OUT_ * OUT_);   //  896 B

  pack_w_kernel<<<dim3(COP), 256, 0, stream>>>(off_w, off_b, attn_w, attn_b,
                                               Wp, biasp);
  pack_mat_kernel<<<dim3(256), 256, 0, stream>>>(Wv, Wvb);
  pack_mat_kernel<<<dim3(256), 256, 0, stream>>>(Wo, Wob);
  pack_x_kernel<<<dim3(4, 64, N_), 256, 0, stream>>>(x, xp);
  conv_mfma_kernel<<<dim3(64, 2, N_), 256, 0, stream>>>(xp, Wp, biasp, P);
  gemm256_kernel<0><<<dim3(32, 2, N_), 256, 0, stream>>>(xp, Wvb, vtb, nullptr);
  sample_kernel<<<dim3((N_ * HEADS * HW * 8) / 256), 256, 0, stream>>>(vtb, P,
                                                                       comb);
  gemm256_kernel<1><<<dim3(32, 2, N_), 256, 0, stream>>>(comb, Wob, nullptr,
                                                         out);
}

// Round 10
// 168.854 us; speedup vs baseline: 1.5390x; 1.5390x over previous
//
#include <hip/hip_runtime.h>
#include <math.h>

#define N_    8
#define C_    256
#define H_    64
#define W_    64
#define HW    4096
#define OUT_  256
#define HEADS 8
#define HD    32
#define K2    9
#define OFFCH 144   // HEADS*K2*2
#define AWCH  72    // HEADS*K2
#define COP   224   // padded conv output channels (216 used)
#define KTOT  2304  // 9 taps * 256 c
#define WPROWS 240  // Wp allocated rows (224 real + 16 DMA-overrun pad)
#define AB16  25344 // bf16 offset of B region in conv smem (2*6*66*32)

typedef __bf16 bf16x8 __attribute__((ext_vector_type(8)));
typedef __bf16 bf16x4 __attribute__((ext_vector_type(4)));
typedef float  f32x4  __attribute__((ext_vector_type(4)));

__device__ __forceinline__ void gload_lds16(const void* g, void* l) {
  __builtin_amdgcn_global_load_lds(
      (const __attribute__((address_space(1))) void*)g,
      (__attribute__((address_space(3))) void*)l, 16, 0, 0);
}

// ---------------------------------------------------------------------------
// pack_x: fp32 NCHW -> bf16 NHWC  (xp[n][y][x][c]), LDS 64x64 tile transpose.
// ---------------------------------------------------------------------------
__global__ __launch_bounds__(256) void pack_x_kernel(
    const float* __restrict__ x, __bf16* __restrict__ xp)
{
  const int c0 = blockIdx.x << 6;
  const int y  = blockIdx.y;
  const int n  = blockIdx.z;
  const int tid = threadIdx.x;
  __shared__ float tile[64][65];

  const int tx = tid & 63, tg = tid >> 6;
#pragma unroll
  for (int i = 0; i < 16; ++i) {
    int cl = tg + (i << 2);
    tile[cl][tx] = x[((size_t)(n * C_ + c0 + cl) * H_ + y) * W_ + tx];
  }
  __syncthreads();
#pragma unroll
  for (int i = 0; i < 16; ++i) {
    int xl = tg + (i << 2);
    xp[((size_t)(n * HW) + y * W_ + xl) * C_ + c0 + tx] = (__bf16)tile[tx][xl];
  }
}

// ---------------------------------------------------------------------------
// pack_w: conv weights -> bf16 Wp[240][tap][c] (tap-major K), + bias, + zbuf.
// ---------------------------------------------------------------------------
__global__ __launch_bounds__(256) void pack_w_kernel(
    const float* __restrict__ off_w, const float* __restrict__ off_b,
    const float* __restrict__ attn_w, const float* __restrict__ attn_b,
    __bf16* __restrict__ Wp, float* __restrict__ biasp,
    __bf16* __restrict__ zbuf)
{
  const int co = blockIdx.x;
  const int c  = threadIdx.x;
  if (co == 0) {  // zero page for OOB halo DMA (4096 B)
    *(uint4*)&zbuf[(size_t)c * 8] = make_uint4(0u, 0u, 0u, 0u);
  }
  const float* base = nullptr;
  if (co < OFFCH)      base = off_w  + ((size_t)co * C_ + c) * 9;
  else if (co < 216)   base = attn_w + ((size_t)(co - OFFCH) * C_ + c) * 9;
#pragma unroll
  for (int t = 0; t < 9; ++t) {
    float w = base ? base[t] : 0.f;
    Wp[(size_t)co * KTOT + t * C_ + c] = (__bf16)w;
  }
  if (c == 0) {
    float b = 0.f;
    if (co < OFFCH) b = off_b[co];
    else if (co < 216) b = attn_b[co - OFFCH];
    biasp[co] = b;
  }
}

// 256x256 fp32 -> bf16 row-major
__global__ __launch_bounds__(256) void pack_mat_kernel(
    const float* __restrict__ Wsrc, __bf16* __restrict__ Wdst)
{
  const int i = blockIdx.x * 256 + threadIdx.x;
  Wdst[i] = (__bf16)Wsrc[i];
}

// ---------------------------------------------------------------------------
// conv_mfma R10: implicit-GEMM 3x3 conv, 16x16x32 bf16 MFMA.
// Block = 256 spatial (4 image rows) x 112 co; grid (16,2,8)=256 -> 1 blk/CU.
// Wave = 1 image row, 4 Mtiles x 7 Ntiles = 28 MFMA/tap.
// ALL staging via global_load_lds (linear LDS; source chunk-XOR pre-swizzle
// -> conflict-free ds_read_b128). B: 3 rotating bufs staged 2 taps ahead.
// A: dbuf per c-slice staged 9 taps ahead. Raw s_barrier + counted vmcnt.
// LDS layout (bf16 units):
//   A(buf,r,col): ((buf*6+r)*66+col)*32 + p*8, p = lg ^ ((col>>1)&3)
//   B(buf,co):    AB16 + buf*4096 + co*32 + p*8, p = lg ^ ((co>>1)&3)
// ---------------------------------------------------------------------------
__global__ __launch_bounds__(256) void conv_mfma_kernel(
    const __bf16* __restrict__ xp, const __bf16* __restrict__ Wp,
    const float* __restrict__ biasp, const __bf16* __restrict__ zbuf,
    __bf16* __restrict__ P)
{
  const int yt = blockIdx.x;          // 0..15 -> rows y0..y0+3
  const int bn = blockIdx.y;          // co half
  const int n  = blockIdx.z;
  const int y0 = yt << 2;
  const int tid = threadIdx.x;
  const int lw = tid & 63, wv = tid >> 6;
  const int lr = lw & 15, lg = lw >> 4;

  __shared__ __align__(16) __bf16 smem[2 * 6 * 66 * 32 + 3 * 128 * 32];

  f32x4 acc[4][7];
#pragma unroll
  for (int m = 0; m < 4; ++m)
#pragma unroll
    for (int nt = 0; nt < 7; ++nt) acc[m][nt] = (f32x4){0.f, 0.f, 0.f, 0.f};

  // zero halo columns 0 and 65 of all 2x6 A rows (written once, never DMA'd)
  if (tid < 96) {
    int p = tid & 3, cs = (tid >> 2) & 1, r = (tid >> 3) % 6, buf = tid / 48;
    int col = cs ? 65 : 0;
    *(uint4*)&smem[((buf * 6 + r) * 66 + col) * 32 + p * 8] =
        make_uint4(0u, 0u, 0u, 0u);
  }

  // ---- DMA staging helpers (wave-uniform LDS window; per-lane global src) --
  auto stage_B = [&](int T) {          // flat tap T -> Bsl[T%3]
    const int ci = T / 9, t = T - ci * 9, buf = T % 3;
    const size_t wbase = (size_t)(bn * 112) * KTOT + t * C_ + (ci << 5);
#pragma unroll
    for (int jj = 0; jj < 2; ++jj) {
      const int j  = (wv << 1) + jj;             // 0..7 (16 co rows each)
      const int co = (j << 4) + (lw >> 2);
      const int cg = (lw & 3) ^ ((co >> 1) & 3); // inverse of read swizzle
      gload_lds16(Wp + wbase + (size_t)co * KTOT + (cg << 3),
                  &smem[AB16 + buf * 4096 + (j << 9)]);
    }
  };
  auto stage_A = [&](int cin) {        // slice cin -> A buf cin&1
    const int buf = cin & 1, c0 = cin << 5;
#pragma unroll
    for (int k = 0; k < 6; ++k) {
      const int idx = wv * 6 + k;                // 0..23
      const int r = idx >> 2, j = idx & 3;       // row 0..5, x-quarter 0..3
      const int y = y0 - 1 + r;
      const int col = 1 + (j << 4) + (lw >> 2);
      const int cg = (lw & 3) ^ ((col >> 1) & 3);
      const __bf16* src = ((unsigned)y < (unsigned)H_)
          ? xp + ((size_t)(n * HW) + y * W_ + (col - 1)) * C_ + c0 + (cg << 3)
          : zbuf;
      gload_lds16(src, &smem[((buf * 6 + r) * 66 + 1 + (j << 4)) * 32]);
    }
  };

  // ---- prologue: A(0), B(0), B(1); full drain; barrier ----
  stage_A(0);
  stage_B(0);
  stage_B(1);
  asm volatile("s_waitcnt vmcnt(0) lgkmcnt(0)" ::: "memory");
  __builtin_amdgcn_s_barrier();
  asm volatile("" ::: "memory");

  // ---- main loop: 72 flat taps ----
  for (int T = 0; T < 72; ++T) {
    const int ci = T / 9, t = T - ci * 9;
    const int abuf = ci & 1, bbuf = T % 3;

    if (T + 2 < 72) stage_B(T + 2);
    if (t == 0 && ci < 7) stage_A(ci + 1);

    // ---- 28 MFMAs for tap t ----
    const int dy = t / 3, dxp = t - dy * 3;
    const int rr = wv + dy;                      // A row index 0..5
    bf16x8 a[4], b[7];
#pragma unroll
    for (int m = 0; m < 4; ++m) {
      const int col = (m << 4) + lr + dxp;       // 0..65
      const int p = lg ^ ((col >> 1) & 3);
      a[m] = *(const bf16x8*)&smem[((abuf * 6 + rr) * 66 + col) * 32 + p * 8];
    }
#pragma unroll
    for (int nt = 0; nt < 7; ++nt) {
      const int co = (nt << 4) + lr;
      const int p = lg ^ ((co >> 1) & 3);
      b[nt] = *(const bf16x8*)&smem[AB16 + bbuf * 4096 + co * 32 + p * 8];
    }
    __builtin_amdgcn_s_setprio(1);
#pragma unroll
    for (int m = 0; m < 4; ++m)
#pragma unroll
      for (int nt = 0; nt < 7; ++nt)
        acc[m][nt] =
            __builtin_amdgcn_mfma_f32_16x16x32_bf16(a[m], b[nt], acc[m][nt], 0, 0, 0);
    __builtin_amdgcn_s_setprio(0);

    // ---- counted-vmcnt barrier: keep the 2-ahead loads in flight ----
    if (T < 71) {
      const int vm = (T >= 70) ? 0 : ((t <= 1 && ci < 7) ? 8 : 2);
      if (vm == 8)      asm volatile("s_waitcnt vmcnt(8)" ::: "memory");
      else if (vm == 2) asm volatile("s_waitcnt vmcnt(2)" ::: "memory");
      else              asm volatile("s_waitcnt vmcnt(0)" ::: "memory");
      __builtin_amdgcn_s_barrier();
      asm volatile("" ::: "memory");
    }
  }

  // ---- epilogue: bias (+ sigmoid for co>=144), store bf16 P[n][s][co] ----
  const int yout = y0 + wv;
#pragma unroll
  for (int nt = 0; nt < 7; ++nt) {
    const int co = bn * 112 + (nt << 4) + lr;
    const float bias = biasp[co];
#pragma unroll
    for (int m = 0; m < 4; ++m) {
#pragma unroll
      for (int reg = 0; reg < 4; ++reg) {
        const int xo = (m << 4) + (lg << 2) + reg;
        float v = acc[m][nt][reg] + bias;
        if (co >= OFFCH) v = 1.f / (1.f + expf(-v));
        P[((size_t)n * HW + yout * W_ + xo) * COP + co] = (__bf16)v;
      }
    }
  }
}

// ---------------------------------------------------------------------------
// gemm256: D[n][s][co] = sum_c A[n][s][c]*Wb[co][c]
// MODE 0: store bf16 NHWC (vproj -> vtb). MODE 1: store fp32 NCHW (wo -> out).
// ---------------------------------------------------------------------------
template <int MODE>
__global__ __launch_bounds__(256) void gemm256_kernel(
    const __bf16* __restrict__ A, const __bf16* __restrict__ Wb,
    __bf16* __restrict__ out_b, float* __restrict__ out_f)
{
  const int st = blockIdx.x;
  const int bn = blockIdx.y;
  const int n  = blockIdx.z;
  const int s0 = st << 7;
  const int tid = threadIdx.x;

  __shared__ __bf16 Asl[128][40];
  __shared__ __bf16 Bsl[128][40];

  const int lw = tid & 63, wv = tid >> 6;
  const int lr = lw & 15, lg = lw >> 4;
  const int sm_base = wv << 5;

  f32x4 acc[2][8];
#pragma unroll
  for (int m = 0; m < 2; ++m)
#pragma unroll
    for (int nt = 0; nt < 8; ++nt) acc[m][nt] = (f32x4){0.f, 0.f, 0.f, 0.f};

  for (int c0 = 0; c0 < 256; c0 += 32) {
    __syncthreads();
#pragma unroll
    for (int it = 0; it < 2; ++it) {
      int i = tid + (it << 8);
      int cg = i & 3, r = i >> 2;
      *(uint4*)&Asl[r][cg << 3] =
          *(const uint4*)&A[((size_t)n * HW + s0 + r) * 256 + c0 + (cg << 3)];
    }
#pragma unroll
    for (int it = 0; it < 2; ++it) {
      int i = tid + (it << 8);
      int cg = i & 3, r = i >> 2;
      *(uint4*)&Bsl[r][cg << 3] =
          *(const uint4*)&Wb[(size_t)((bn << 7) + r) * 256 + c0 + (cg << 3)];
    }
    __syncthreads();

    bf16x8 a0 = *(const bf16x8*)&Asl[sm_base + lr][lg << 3];
    bf16x8 a1 = *(const bf16x8*)&Asl[sm_base + 16 + lr][lg << 3];
#pragma unroll
    for (int nt = 0; nt < 8; ++nt) {
      bf16x8 b = *(const bf16x8*)&Bsl[(nt << 4) + lr][lg << 3];
      acc[0][nt] = __builtin_amdgcn_mfma_f32_16x16x32_bf16(a0, b, acc[0][nt], 0, 0, 0);
      acc[1][nt] = __builtin_amdgcn_mfma_f32_16x16x32_bf16(a1, b, acc[1][nt], 0, 0, 0);
    }
  }

#pragma unroll
  for (int m = 0; m < 2; ++m) {
#pragma unroll
    for (int nt = 0; nt < 8; ++nt) {
      const int co = (bn << 7) + (nt << 4) + lr;
      if (MODE == 0) {
#pragma unroll
        for (int reg = 0; reg < 4; ++reg) {
          const int sm = sm_base + (m << 4) + (lg << 2) + reg;
          out_b[((size_t)n * HW + s0 + sm) * 256 + co] = (__bf16)acc[m][nt][reg];
        }
      } else {
        const int sm = sm_base + (m << 4) + (lg << 2);
        float4 v4 = make_float4(acc[m][nt][0], acc[m][nt][1],
                                acc[m][nt][2], acc[m][nt][3]);
        *(float4*)&out_f[((size_t)(n * 256 + co)) * HW + s0 + sm] = v4;
      }
    }
  }
}

// ---------------------------------------------------------------------------
// Deformable sampling, channel-split: 8 lanes per (n,h,s), each owns 4 ch.
// ---------------------------------------------------------------------------
__global__ __launch_bounds__(256) void sample_kernel(
    const __bf16* __restrict__ vtb, const __bf16* __restrict__ P,
    __bf16* __restrict__ comb)
{
  const int gid = blockIdx.x * 256 + threadIdx.x;
  const int cg  = gid & 7;
  const int q   = gid >> 3;
  const int s = q & (HW - 1);
  const int h = (q >> 12) & (HEADS - 1);
  const int n = q >> 15;
  const int yq = s >> 6, xq = s & 63;

  float a0 = 0.f, a1 = 0.f, a2 = 0.f, a3 = 0.f;

  const __bf16* prow  = P + ((size_t)n * HW + s) * COP;
  const __bf16* vbase = vtb + ((size_t)n * HW) * OUT_ + h * HD + (cg << 2);

#pragma unroll
  for (int k = 0; k < K2; ++k) {
    const float offx = (float)prow[18 * h + 2 * k];
    const float offy = (float)prow[18 * h + 2 * k + 1];
    const float a    = (float)prow[OFFCH + 9 * h + k];

    const float xpf = (float)xq + offx * (63.f / 64.f);
    const float ypf = (float)yq + offy * (63.f / 64.f);
    const float fx0 = floorf(xpf), fy0 = floorf(ypf);
    const int x0 = (int)fx0, y0 = (int)fy0;
    const float wx1 = xpf - fx0, wx0 = 1.f - wx1;
    const float wy1 = ypf - fy0, wy0 = 1.f - wy1;

#pragma unroll
    for (int cy = 0; cy < 2; ++cy) {
      const int yi = y0 + cy;
      if ((unsigned)yi >= (unsigned)H_) continue;
      const float wy = cy ? wy1 : wy0;
#pragma unroll
      for (int cx = 0; cx < 2; ++cx) {
        const int xi = x0 + cx;
        if ((unsigned)xi >= (unsigned)W_) continue;
        const float cw = a * wy * (cx ? wx1 : wx0);
        bf16x4 v = *(const bf16x4*)(vbase + (size_t)(yi * W_ + xi) * OUT_);
        a0 = fmaf(cw, (float)v[0], a0);
        a1 = fmaf(cw, (float)v[1], a1);
        a2 = fmaf(cw, (float)v[2], a2);
        a3 = fmaf(cw, (float)v[3], a3);
      }
    }
  }

  bf16x4 r;
  r[0] = (__bf16)a0; r[1] = (__bf16)a1; r[2] = (__bf16)a2; r[3] = (__bf16)a3;
  *(bf16x4*)&comb[((size_t)n * HW + s) * OUT_ + h * HD + (cg << 2)] = r;
}

// ---------------------------------------------------------------------------
extern "C" void kernel_launch(void* const* d_in, const int* in_sizes, int n_in,
                              void* d_out, int out_size, void* d_ws,
                              size_t ws_size, hipStream_t stream)
{
  const float* x      = (const float*)d_in[0];
  // d_in[1] = Wq, d_in[2] = Wk : dead code (q,k unused in reference)
  const float* Wv     = (const float*)d_in[3];
  const float* off_w  = (const float*)d_in[4];
  const float* off_b  = (const float*)d_in[5];
  const float* attn_w = (const float*)d_in[6];
  const float* attn_b = (const float*)d_in[7];
  const float* Wo     = (const float*)d_in[8];
  float* out = (float*)d_out;

  __bf16* vtb   = (__bf16*)d_ws;                         // 16.78 MB
  __bf16* xp    = vtb + (size_t)N_ * HW * OUT_;          // 16.78 MB
  __bf16* comb  = xp + (size_t)N_ * HW * C_;             // 16.78 MB
  __bf16* P     = comb + (size_t)N_ * HW * OUT_;         // 14.68 MB
  __bf16* Wp    = P + (size_t)N_ * HW * COP;             //  1.11 MB (240 rows)
  __bf16* Wvb   = Wp + (size_t)WPROWS * KTOT;            //  128 KB
  __bf16* Wob   = Wvb + (size_t)OUT_ * C_;               //  128 KB
  __bf16* zbuf  = Wob + (size_t)OUT_ * OUT_;             //  4 KB zero page
  float*  biasp = (float*)(zbuf + 2048);                 //  896 B

  pack_w_kernel<<<dim3(COP), 256, 0, stream>>>(off_w, off_b, attn_w, attn_b,
                                               Wp, biasp, zbuf);
  pack_mat_kernel<<<dim3(256), 256, 0, stream>>>(Wv, Wvb);
  pack_mat_kernel<<<dim3(256), 256, 0, stream>>>(Wo, Wob);
  pack_x_kernel<<<dim3(4, 64, N_), 256, 0, stream>>>(x, xp);
  conv_mfma_kernel<<<dim3(16, 2, N_), 256, 0, stream>>>(xp, Wp, biasp, zbuf, P);
  gemm256_kernel<0><<<dim3(32, 2, N_), 256, 0, stream>>>(xp, Wvb, vtb, nullptr);
  sample_kernel<<<dim3((N_ * HEADS * HW * 8) / 256), 256, 0, stream>>>(vtb, P,
                                                                       comb);
  gemm256_kernel<1><<<dim3(32, 2, N_), 256, 0, stream>>>(comb, Wob, nullptr,
                                                         out);
}

// Round 12
// 150.422 us; speedup vs baseline: 1.7276x; 1.1225x over previous
//
#include <hip/hip_runtime.h>
#include <math.h>

#define N_    8
#define C_    256
#define H_    64
#define W_    64
#define HW    4096
#define OUT_  256
#define HEADS 8
#define HD    32
#define K2    9
#define OFFCH 144   // HEADS*K2*2
#define AWCH  72    // HEADS*K2
#define KTOT  2304  // 9 taps * 256 c
#define WPROWS 240  // Wp allocated rows (224 real + 16 DMA-overrun pad)
#define AB16  25344 // bf16 offset of B region in conv smem (2*6*66*32)

typedef __bf16 bf16x8 __attribute__((ext_vector_type(8)));
typedef __bf16 bf16x4 __attribute__((ext_vector_type(4)));
typedef float  f32x4  __attribute__((ext_vector_type(4)));

__device__ __forceinline__ void gload_lds16(const void* g, void* l) {
  __builtin_amdgcn_global_load_lds(
      (const __attribute__((address_space(1))) void*)g,
      (__attribute__((address_space(3))) void*)l, 16, 0, 0);
}

// ---------------------------------------------------------------------------
// pack_x: fp32 NCHW -> bf16 NHWC  (xp[n][y][x][c]), LDS 64x64 tile transpose.
// ---------------------------------------------------------------------------
__global__ __launch_bounds__(256) void pack_x_kernel(
    const float* __restrict__ x, __bf16* __restrict__ xp)
{
  const int c0 = blockIdx.x << 6;
  const int y  = blockIdx.y;
  const int n  = blockIdx.z;
  const int tid = threadIdx.x;
  __shared__ float tile[64][65];

  const int tx = tid & 63, tg = tid >> 6;
#pragma unroll
  for (int i = 0; i < 16; ++i) {
    int cl = tg + (i << 2);
    tile[cl][tx] = x[((size_t)(n * C_ + c0 + cl) * H_ + y) * W_ + tx];
  }
  __syncthreads();
#pragma unroll
  for (int i = 0; i < 16; ++i) {
    int xl = tg + (i << 2);
    xp[((size_t)(n * HW) + y * W_ + xl) * C_ + c0 + tx] = (__bf16)tile[tx][xl];
  }
}

// ---------------------------------------------------------------------------
// pack_w: conv weights -> bf16 Wp[240][tap][c] (tap-major K), + bias, + zbuf.
// ---------------------------------------------------------------------------
__global__ __launch_bounds__(256) void pack_w_kernel(
    const float* __restrict__ off_w, const float* __restrict__ off_b,
    const float* __restrict__ attn_w, const float* __restrict__ attn_b,
    __bf16* __restrict__ Wp, float* __restrict__ biasp,
    __bf16* __restrict__ zbuf)
{
  const int co = blockIdx.x;
  const int c  = threadIdx.x;
  if (co == 0) {  // zero page for OOB halo DMA (4096 B)
    *(uint4*)&zbuf[(size_t)c * 8] = make_uint4(0u, 0u, 0u, 0u);
  }
  const float* base = nullptr;
  if (co < OFFCH)      base = off_w  + ((size_t)co * C_ + c) * 9;
  else if (co < 216)   base = attn_w + ((size_t)(co - OFFCH) * C_ + c) * 9;
#pragma unroll
  for (int t = 0; t < 9; ++t) {
    float w = base ? base[t] : 0.f;
    Wp[(size_t)co * KTOT + t * C_ + c] = (__bf16)w;
  }
  if (c == 0) {
    float b = 0.f;
    if (co < OFFCH) b = off_b[co];
    else if (co < 216) b = attn_b[co - OFFCH];
    biasp[co] = b;
  }
}

// 256x256 fp32 -> bf16 row-major
__global__ __launch_bounds__(256) void pack_mat_kernel(
    const float* __restrict__ Wsrc, __bf16* __restrict__ Wdst)
{
  const int i = blockIdx.x * 256 + threadIdx.x;
  Wdst[i] = (__bf16)Wsrc[i];
}

// ---------------------------------------------------------------------------
// conv_mfma (R10 structure, P2 head-packed epilogue):
// Block = 256 spatial x 112 co; grid (16,2,8)=256 -> 1 blk/CU.
// global_load_lds staging, 3 rotating B bufs 2 taps ahead, A dbuf 9 ahead,
// raw s_barrier + counted vmcnt.
// ---------------------------------------------------------------------------
__global__ __launch_bounds__(256) void conv_mfma_kernel(
    const __bf16* __restrict__ xp, const __bf16* __restrict__ Wp,
    const float* __restrict__ biasp, const __bf16* __restrict__ zbuf,
    __bf16* __restrict__ P2)
{
  const int yt = blockIdx.x;
  const int bn = blockIdx.y;
  const int n  = blockIdx.z;
  const int y0 = yt << 2;
  const int tid = threadIdx.x;
  const int lw = tid & 63, wv = tid >> 6;
  const int lr = lw & 15, lg = lw >> 4;

  __shared__ __align__(16) __bf16 smem[2 * 6 * 66 * 32 + 3 * 128 * 32];

  f32x4 acc[4][7];
#pragma unroll
  for (int m = 0; m < 4; ++m)
#pragma unroll
    for (int nt = 0; nt < 7; ++nt) acc[m][nt] = (f32x4){0.f, 0.f, 0.f, 0.f};

  if (tid < 96) {
    int p = tid & 3, cs = (tid >> 2) & 1, r = (tid >> 3) % 6, buf = tid / 48;
    int col = cs ? 65 : 0;
    *(uint4*)&smem[((buf * 6 + r) * 66 + col) * 32 + p * 8] =
        make_uint4(0u, 0u, 0u, 0u);
  }

  auto stage_B = [&](int T) {
    const int ci = T / 9, t = T - ci * 9, buf = T % 3;
    const size_t wbase = (size_t)(bn * 112) * KTOT + t * C_ + (ci << 5);
#pragma unroll
    for (int jj = 0; jj < 2; ++jj) {
      const int j  = (wv << 1) + jj;
      const int co = (j << 4) + (lw >> 2);
      const int cg = (lw & 3) ^ ((co >> 1) & 3);
      gload_lds16(Wp + wbase + (size_t)co * KTOT + (cg << 3),
                  &smem[AB16 + buf * 4096 + (j << 9)]);
    }
  };
  auto stage_A = [&](int cin) {
    const int buf = cin & 1, c0 = cin << 5;
#pragma unroll
    for (int k = 0; k < 6; ++k) {
      const int idx = wv * 6 + k;
      const int r = idx >> 2, j = idx & 3;
      const int y = y0 - 1 + r;
      const int col = 1 + (j << 4) + (lw >> 2);
      const int cg = (lw & 3) ^ ((col >> 1) & 3);
      const __bf16* src = ((unsigned)y < (unsigned)H_)
          ? xp + ((size_t)(n * HW) + y * W_ + (col - 1)) * C_ + c0 + (cg << 3)
          : zbuf;
      gload_lds16(src, &smem[((buf * 6 + r) * 66 + 1 + (j << 4)) * 32]);
    }
  };

  stage_A(0);
  stage_B(0);
  stage_B(1);
  asm volatile("s_waitcnt vmcnt(0) lgkmcnt(0)" ::: "memory");
  __builtin_amdgcn_s_barrier();
  asm volatile("" ::: "memory");

  for (int T = 0; T < 72; ++T) {
    const int ci = T / 9, t = T - ci * 9;
    const int abuf = ci & 1, bbuf = T % 3;

    if (T + 2 < 72) stage_B(T + 2);
    if (t == 0 && ci < 7) stage_A(ci + 1);

    const int dy = t / 3, dxp = t - dy * 3;
    const int rr = wv + dy;
    bf16x8 a[4], b[7];
#pragma unroll
    for (int m = 0; m < 4; ++m) {
      const int col = (m << 4) + lr + dxp;
      const int p = lg ^ ((col >> 1) & 3);
      a[m] = *(const bf16x8*)&smem[((abuf * 6 + rr) * 66 + col) * 32 + p * 8];
    }
#pragma unroll
    for (int nt = 0; nt < 7; ++nt) {
      const int co = (nt << 4) + lr;
      const int p = lg ^ ((co >> 1) & 3);
      b[nt] = *(const bf16x8*)&smem[AB16 + bbuf * 4096 + co * 32 + p * 8];
    }
    __builtin_amdgcn_s_setprio(1);
#pragma unroll
    for (int m = 0; m < 4; ++m)
#pragma unroll
      for (int nt = 0; nt < 7; ++nt)
        acc[m][nt] =
            __builtin_amdgcn_mfma_f32_16x16x32_bf16(a[m], b[nt], acc[m][nt], 0, 0, 0);
    __builtin_amdgcn_s_setprio(0);

    if (T < 71) {
      const int vm = (T >= 70) ? 0 : ((t <= 1 && ci < 7) ? 8 : 2);
      if (vm == 8)      asm volatile("s_waitcnt vmcnt(8)" ::: "memory");
      else if (vm == 2) asm volatile("s_waitcnt vmcnt(2)" ::: "memory");
      else              asm volatile("s_waitcnt vmcnt(0)" ::: "memory");
      __builtin_amdgcn_s_barrier();
      asm volatile("" ::: "memory");
    }
  }

  // ---- epilogue: bias (+ sigmoid), head-packed store to P2[n][s][32h+j] ----
  const int yout = y0 + wv;
#pragma unroll
  for (int nt = 0; nt < 7; ++nt) {
    const int co = bn * 112 + (nt << 4) + lr;
    if (co < 216) {
      const float bias = biasp[co];
      int idx;
      if (co < OFFCH) {
        int hh = co / 18;
        idx = (hh << 5) + (co - 18 * hh);
      } else {
        int r = co - OFFCH;
        int hh = r / 9;
        idx = (hh << 5) + 18 + (r - 9 * hh);
      }
#pragma unroll
      for (int m = 0; m < 4; ++m) {
#pragma unroll
        for (int reg = 0; reg < 4; ++reg) {
          const int xo = (m << 4) + (lg << 2) + reg;
          float v = acc[m][nt][reg] + bias;
          if (co >= OFFCH) v = 1.f / (1.f + expf(-v));
          P2[((size_t)n * HW + yout * W_ + xo) * 256 + idx] = (__bf16)v;
        }
      }
    }
  }
}

// ---------------------------------------------------------------------------
// gemm256: D[n][s][co] = sum_c A[n][s][c]*Wb[co][c]
// MODE 0: store bf16 NHWC (vproj -> vtb). MODE 1: store fp32 NCHW (wo -> out).
// ---------------------------------------------------------------------------
template <int MODE>
__global__ __launch_bounds__(256) void gemm256_kernel(
    const __bf16* __restrict__ A, const __bf16* __restrict__ Wb,
    __bf16* __restrict__ out_b, float* __restrict__ out_f)
{
  const int st = blockIdx.x;
  const int bn = blockIdx.y;
  const int n  = blockIdx.z;
  const int s0 = st << 7;
  const int tid = threadIdx.x;

  __shared__ __bf16 Asl[128][40];
  __shared__ __bf16 Bsl[128][40];

  const int lw = tid & 63, wv = tid >> 6;
  const int lr = lw & 15, lg = lw >> 4;
  const int sm_base = wv << 5;

  f32x4 acc[2][8];
#pragma unroll
  for (int m = 0; m < 2; ++m)
#pragma unroll
    for (int nt = 0; nt < 8; ++nt) acc[m][nt] = (f32x4){0.f, 0.f, 0.f, 0.f};

  for (int c0 = 0; c0 < 256; c0 += 32) {
    __syncthreads();
#pragma unroll
    for (int it = 0; it < 2; ++it) {
      int i = tid + (it << 8);
      int cg = i & 3, r = i >> 2;
      *(uint4*)&Asl[r][cg << 3] =
          *(const uint4*)&A[((size_t)n * HW + s0 + r) * 256 + c0 + (cg << 3)];
    }
#pragma unroll
    for (int it = 0; it < 2; ++it) {
      int i = tid + (it << 8);
      int cg = i & 3, r = i >> 2;
      *(uint4*)&Bsl[r][cg << 3] =
          *(const uint4*)&Wb[(size_t)((bn << 7) + r) * 256 + c0 + (cg << 3)];
    }
    __syncthreads();

    bf16x8 a0 = *(const bf16x8*)&Asl[sm_base + lr][lg << 3];
    bf16x8 a1 = *(const bf16x8*)&Asl[sm_base + 16 + lr][lg << 3];
#pragma unroll
    for (int nt = 0; nt < 8; ++nt) {
      bf16x8 b = *(const bf16x8*)&Bsl[(nt << 4) + lr][lg << 3];
      acc[0][nt] = __builtin_amdgcn_mfma_f32_16x16x32_bf16(a0, b, acc[0][nt], 0, 0, 0);
      acc[1][nt] = __builtin_amdgcn_mfma_f32_16x16x32_bf16(a1, b, acc[1][nt], 0, 0, 0);
    }
  }

#pragma unroll
  for (int m = 0; m < 2; ++m) {
#pragma unroll
    for (int nt = 0; nt < 8; ++nt) {
      const int co = (bn << 7) + (nt << 4) + lr;
      if (MODE == 0) {
#pragma unroll
        for (int reg = 0; reg < 4; ++reg) {
          const int sm = sm_base + (m << 4) + (lg << 2) + reg;
          out_b[((size_t)n * HW + s0 + sm) * 256 + co] = (__bf16)acc[m][nt][reg];
        }
      } else {
        const int sm = sm_base + (m << 4) + (lg << 2);
        float4 v4 = make_float4(acc[m][nt][0], acc[m][nt][1],
                                acc[m][nt][2], acc[m][nt][3]);
        *(float4*)&out_f[((size_t)(n * 256 + co)) * HW + s0 + sm] = v4;
      }
    }
  }
}

// ---------------------------------------------------------------------------
// Deformable sampling R11: 4 lanes per (n,h,s), 8 channels each (bf16x8).
// P params read as 4 vector loads from head-packed P2 (27 contiguous bf16).
// ---------------------------------------------------------------------------
__global__ __launch_bounds__(256) void sample_kernel(
    const __bf16* __restrict__ vtb, const __bf16* __restrict__ P2,
    __bf16* __restrict__ comb)
{
  const int gid = blockIdx.x * 256 + threadIdx.x;
  const int cg  = gid & 3;        // channel oct within head
  const int q   = gid >> 2;       // point index
  const int s = q & (HW - 1);
  const int h = (q >> 12) & (HEADS - 1);
  const int n = q >> 15;
  const int yq = s >> 6, xq = s & 63;

  // packed params: [offx,offy]*9 at 0..17, aw*9 at 18..26 (64B-aligned block)
  const __bf16* prow = P2 + ((size_t)n * HW + s) * 256 + (h << 5);
  bf16x8 p0 = *(const bf16x8*)(prow);       // pairs k=0..3
  bf16x8 p1 = *(const bf16x8*)(prow + 8);   // pairs k=4..7
  bf16x8 p2 = *(const bf16x8*)(prow + 16);  // pair k=8; aw k=0..5
  bf16x4 p3 = *(const bf16x4*)(prow + 24);  // aw k=6..8

  float acc[8];
#pragma unroll
  for (int j = 0; j < 8; ++j) acc[j] = 0.f;

  const __bf16* vbase = vtb + ((size_t)n * HW) * 256 + (h << 5) + (cg << 3);

#pragma unroll
  for (int k = 0; k < K2; ++k) {
    float offx, offy, a;
    if (k < 4)      { offx = (float)p0[2 * k];       offy = (float)p0[2 * k + 1]; }
    else if (k < 8) { offx = (float)p1[2 * (k - 4)]; offy = (float)p1[2 * (k - 4) + 1]; }
    else            { offx = (float)p2[0];           offy = (float)p2[1]; }
    if (k < 6)      a = (float)p2[2 + k];
    else            a = (float)p3[k - 6];

    const float xpf = (float)xq + offx * (63.f / 64.f);
    const float ypf = (float)yq + offy * (63.f / 64.f);
    const float fx0 = floorf(xpf), fy0 = floorf(ypf);
    const int x0 = (int)fx0, y0 = (int)fy0;
    const float wx1 = xpf - fx0, wx0 = 1.f - wx1;
    const float wy1 = ypf - fy0, wy0 = 1.f - wy1;

#pragma unroll
    for (int cy = 0; cy < 2; ++cy) {
      const int yi = y0 + cy;
      if ((unsigned)yi >= (unsigned)H_) continue;
      const float wy = cy ? wy1 : wy0;
#pragma unroll
      for (int cx = 0; cx < 2; ++cx) {
        const int xi = x0 + cx;
        if ((unsigned)xi >= (unsigned)W_) continue;
        const float cw = a * wy * (cx ? wx1 : wx0);
        bf16x8 v = *(const bf16x8*)(vbase + (size_t)(yi * W_ + xi) * 256);
#pragma unroll
        for (int j = 0; j < 8; ++j) acc[j] = fmaf(cw, (float)v[j], acc[j]);
      }
    }
  }

  bf16x8 r;
#pragma unroll
  for (int j = 0; j < 8; ++j) r[j] = (__bf16)acc[j];
  *(bf16x8*)&comb[((size_t)n * HW + s) * 256 + (h << 5) + (cg << 3)] = r;
}

// ---------------------------------------------------------------------------
extern "C" void kernel_launch(void* const* d_in, const int* in_sizes, int n_in,
                              void* d_out, int out_size, void* d_ws,
                              size_t ws_size, hipStream_t stream)
{
  const float* x      = (const float*)d_in[0];
  // d_in[1] = Wq, d_in[2] = Wk : dead code (q,k unused in reference)
  const float* Wv     = (const float*)d_in[3];
  const float* off_w  = (const float*)d_in[4];
  const float* off_b  = (const float*)d_in[5];
  const float* attn_w = (const float*)d_in[6];
  const float* attn_b = (const float*)d_in[7];
  const float* Wo     = (const float*)d_in[8];
  float* out = (float*)d_out;

  __bf16* vtb   = (__bf16*)d_ws;                         // 16.78 MB
  __bf16* xp    = vtb + (size_t)N_ * HW * OUT_;          // 16.78 MB
  __bf16* comb  = xp + (size_t)N_ * HW * C_;             // 16.78 MB
  __bf16* P2    = comb + (size_t)N_ * HW * OUT_;         // 16.78 MB (head-packed)
  __bf16* Wp    = P2 + (size_t)N_ * HW * 256;            //  1.11 MB (240 rows)
  __bf16* Wvb   = Wp + (size_t)WPROWS * KTOT;            //  128 KB
  __bf16* Wob   = Wvb + (size_t)OUT_ * C_;               //  128 KB
  __bf16* zbuf  = Wob + (size_t)OUT_ * OUT_;             //  4 KB zero page
  float*  biasp = (float*)(zbuf + 2048);                 //  896 B

  pack_w_kernel<<<dim3(224), 256, 0, stream>>>(off_w, off_b, attn_w, attn_b,
                                               Wp, biasp, zbuf);
  pack_mat_kernel<<<dim3(256), 256, 0, stream>>>(Wv, Wvb);
  pack_mat_kernel<<<dim3(256), 256, 0, stream>>>(Wo, Wob);
  pack_x_kernel<<<dim3(4, 64, N_), 256, 0, stream>>>(x, xp);
  conv_mfma_kernel<<<dim3(16, 2, N_), 256, 0, stream>>>(xp, Wp, biasp, zbuf, P2);
  gemm256_kernel<0><<<dim3(32, 2, N_), 256, 0, stream>>>(xp, Wvb, vtb, nullptr);
  sample_kernel<<<dim3((N_ * HEADS * HW * 4) / 256), 256, 0, stream>>>(vtb, P2,
                                                                       comb);
  gemm256_kernel<1><<<dim3(32, 2, N_), 256, 0, stream>>>(comb, Wob, nullptr,
                                                         out);
}

// Round 13
// 143.119 us; speedup vs baseline: 1.8158x; 1.0510x over previous
//
#include <hip/hip_runtime.h>
#include <math.h>

#define N_    8
#define C_    256
#define H_    64
#define W_    64
#define HW    4096
#define OUT_  256
#define HEADS 8
#define HD    32
#define K2    9
#define OFFCH 144   // HEADS*K2*2
#define AWCH  72    // HEADS*K2
#define KTOT  2304  // 9 taps * 256 c
#define WPROWS 240  // Wp allocated rows (224 real + 16 DMA-overrun pad)
#define AB16  16896 // bf16 offset of B region in conv smem (2*4*66*32)

typedef __bf16 bf16x8 __attribute__((ext_vector_type(8)));
typedef __bf16 bf16x4 __attribute__((ext_vector_type(4)));
typedef float  f32x4  __attribute__((ext_vector_type(4)));

__device__ __forceinline__ void gload_lds16(const void* g, void* l) {
  __builtin_amdgcn_global_load_lds(
      (const __attribute__((address_space(1))) void*)g,
      (__attribute__((address_space(3))) void*)l, 16, 0, 0);
}

// ---------------------------------------------------------------------------
// pack_x: fp32 NCHW -> bf16 NHWC  (xp[n][y][x][c]), LDS 64x64 tile transpose.
// ---------------------------------------------------------------------------
__global__ __launch_bounds__(256) void pack_x_kernel(
    const float* __restrict__ x, __bf16* __restrict__ xp)
{
  const int c0 = blockIdx.x << 6;
  const int y  = blockIdx.y;
  const int n  = blockIdx.z;
  const int tid = threadIdx.x;
  __shared__ float tile[64][65];

  const int tx = tid & 63, tg = tid >> 6;
#pragma unroll
  for (int i = 0; i < 16; ++i) {
    int cl = tg + (i << 2);
    tile[cl][tx] = x[((size_t)(n * C_ + c0 + cl) * H_ + y) * W_ + tx];
  }
  __syncthreads();
#pragma unroll
  for (int i = 0; i < 16; ++i) {
    int xl = tg + (i << 2);
    xp[((size_t)(n * HW) + y * W_ + xl) * C_ + c0 + tx] = (__bf16)tile[tx][xl];
  }
}

// ---------------------------------------------------------------------------
// pack_w: conv weights -> bf16 Wp[240][tap][c] (tap-major K), + bias, + zbuf.
// ---------------------------------------------------------------------------
__global__ __launch_bounds__(256) void pack_w_kernel(
    const float* __restrict__ off_w, const float* __restrict__ off_b,
    const float* __restrict__ attn_w, const float* __restrict__ attn_b,
    __bf16* __restrict__ Wp, float* __restrict__ biasp,
    __bf16* __restrict__ zbuf)
{
  const int co = blockIdx.x;
  const int c  = threadIdx.x;
  if (co == 0) {  // zero page for OOB halo DMA (4096 B)
    *(uint4*)&zbuf[(size_t)c * 8] = make_uint4(0u, 0u, 0u, 0u);
  }
  const float* base = nullptr;
  if (co < OFFCH)      base = off_w  + ((size_t)co * C_ + c) * 9;
  else if (co < 216)   base = attn_w + ((size_t)(co - OFFCH) * C_ + c) * 9;
#pragma unroll
  for (int t = 0; t < 9; ++t) {
    float w = base ? base[t] : 0.f;
    Wp[(size_t)co * KTOT + t * C_ + c] = (__bf16)w;
  }
  if (c == 0) {
    float b = 0.f;
    if (co < OFFCH) b = off_b[co];
    else if (co < 216) b = attn_b[co - OFFCH];
    biasp[co] = b;
  }
}

// 256x256 fp32 -> bf16 row-major
__global__ __launch_bounds__(256) void pack_mat_kernel(
    const float* __restrict__ Wsrc, __bf16* __restrict__ Wdst)
{
  const int i = blockIdx.x * 256 + threadIdx.x;
  Wdst[i] = (__bf16)Wsrc[i];
}

// ---------------------------------------------------------------------------
// conv_mfma R13: implicit-GEMM 3x3 conv, 16x16x32 bf16 MFMA.
// Block = 128 spatial (2 image rows) x 112 co; grid (32,2,8)=512 -> 2 blk/CU
// (TLP: co-resident block hides barrier/latency stalls - m114).
// Wave = 32 spatial (2 Mtiles) x 7 Ntiles = 14 MFMA/tap.
// global_load_lds staging, 3 rotating B bufs 2 taps ahead, A dbuf 9 ahead,
// raw s_barrier + counted vmcnt. LDS 58.4 KB -> 2 blocks/CU.
// ---------------------------------------------------------------------------
__global__ __launch_bounds__(256) void conv_mfma_kernel(
    const __bf16* __restrict__ xp, const __bf16* __restrict__ Wp,
    const float* __restrict__ biasp, const __bf16* __restrict__ zbuf,
    __bf16* __restrict__ P2)
{
  const int yt = blockIdx.x;          // 0..31 -> rows y0, y0+1
  const int bn = blockIdx.y;          // co half
  const int n  = blockIdx.z;
  const int y0 = yt << 1;
  const int tid = threadIdx.x;
  const int lw = tid & 63, wv = tid >> 6;
  const int lr = lw & 15, lg = lw >> 4;
  const int wrow = wv >> 1;           // wave's image row (0/1)
  const int xb   = (wv & 1) << 5;     // wave's x base (0/32)

  __shared__ __align__(16) __bf16 smem[2 * 4 * 66 * 32 + 3 * 128 * 32];

  f32x4 acc[2][7];
#pragma unroll
  for (int m = 0; m < 2; ++m)
#pragma unroll
    for (int nt = 0; nt < 7; ++nt) acc[m][nt] = (f32x4){0.f, 0.f, 0.f, 0.f};

  // zero halo columns 0 and 65 of all 2x4 A rows (written once, never DMA'd)
  if (tid < 64) {
    int p = tid & 3, cs = (tid >> 2) & 1, r = (tid >> 3) & 3, buf = tid >> 5;
    int col = cs ? 65 : 0;
    *(uint4*)&smem[((buf * 4 + r) * 66 + col) * 32 + p * 8] =
        make_uint4(0u, 0u, 0u, 0u);
  }

  auto stage_B = [&](int T) {          // flat tap T -> Bsl[T%3]
    const int ci = T / 9, t = T - ci * 9, buf = T % 3;
    const size_t wbase = (size_t)(bn * 112) * KTOT + t * C_ + (ci << 5);
#pragma unroll
    for (int jj = 0; jj < 2; ++jj) {
      const int j  = (wv << 1) + jj;             // 0..7 (16 co rows each)
      const int co = (j << 4) + (lw >> 2);
      const int cg = (lw & 3) ^ ((co >> 1) & 3); // inverse of read swizzle
      gload_lds16(Wp + wbase + (size_t)co * KTOT + (cg << 3),
                  &smem[AB16 + buf * 4096 + (j << 9)]);
    }
  };
  auto stage_A = [&](int cin) {        // slice cin -> A buf cin&1
    const int buf = cin & 1, c0 = cin << 5;
#pragma unroll
    for (int k = 0; k < 4; ++k) {      // wave wv stages A row wv, quarter k
      const int r = wv, j = k;
      const int y = y0 - 1 + r;
      const int col = 1 + (j << 4) + (lw >> 2);
      const int cg = (lw & 3) ^ ((col >> 1) & 3);
      const __bf16* src = ((unsigned)y < (unsigned)H_)
          ? xp + ((size_t)(n * HW) + y * W_ + (col - 1)) * C_ + c0 + (cg << 3)
          : zbuf;
      gload_lds16(src, &smem[((buf * 4 + r) * 66 + 1 + (j << 4)) * 32]);
    }
  };

  // ---- prologue: A(0), B(0), B(1); full drain; barrier ----
  stage_A(0);
  stage_B(0);
  stage_B(1);
  asm volatile("s_waitcnt vmcnt(0) lgkmcnt(0)" ::: "memory");
  __builtin_amdgcn_s_barrier();
  asm volatile("" ::: "memory");

  // ---- main loop: 72 flat taps ----
  for (int T = 0; T < 72; ++T) {
    const int ci = T / 9, t = T - ci * 9;
    const int abuf = ci & 1, bbuf = T % 3;

    if (T + 2 < 72) stage_B(T + 2);
    if (t == 0 && ci < 7) stage_A(ci + 1);

    // ---- 14 MFMAs for tap t ----
    const int dy = t / 3, dxp = t - dy * 3;
    const int rr = wrow + dy;                    // A row index 0..3
    bf16x8 a[2], b[7];
#pragma unroll
    for (int m = 0; m < 2; ++m) {
      const int col = xb + (m << 4) + lr + dxp;  // 0..65
      const int p = lg ^ ((col >> 1) & 3);
      a[m] = *(const bf16x8*)&smem[((abuf * 4 + rr) * 66 + col) * 32 + p * 8];
    }
#pragma unroll
    for (int nt = 0; nt < 7; ++nt) {
      const int co = (nt << 4) + lr;
      const int p = lg ^ ((co >> 1) & 3);
      b[nt] = *(const bf16x8*)&smem[AB16 + bbuf * 4096 + co * 32 + p * 8];
    }
    __builtin_amdgcn_s_setprio(1);
#pragma unroll
    for (int m = 0; m < 2; ++m)
#pragma unroll
      for (int nt = 0; nt < 7; ++nt)
        acc[m][nt] =
            __builtin_amdgcn_mfma_f32_16x16x32_bf16(a[m], b[nt], acc[m][nt], 0, 0, 0);
    __builtin_amdgcn_s_setprio(0);

    // ---- counted-vmcnt barrier: keep the ahead-loads in flight ----
    if (T < 71) {
      const int vm = (T >= 70) ? 0 : ((t <= 1 && ci < 7) ? 6 : 2);
      if (vm == 6)      asm volatile("s_waitcnt vmcnt(6)" ::: "memory");
      else if (vm == 2) asm volatile("s_waitcnt vmcnt(2)" ::: "memory");
      else              asm volatile("s_waitcnt vmcnt(0)" ::: "memory");
      __builtin_amdgcn_s_barrier();
      asm volatile("" ::: "memory");
    }
  }

  // ---- epilogue: bias (+ sigmoid), head-packed store to P2[n][s][32h+j] ----
  const int yout = y0 + wrow;
#pragma unroll
  for (int nt = 0; nt < 7; ++nt) {
    const int co = bn * 112 + (nt << 4) + lr;
    if (co < 216) {
      const float bias = biasp[co];
      int idx;
      if (co < OFFCH) {
        int hh = co / 18;
        idx = (hh << 5) + (co - 18 * hh);
      } else {
        int r = co - OFFCH;
        int hh = r / 9;
        idx = (hh << 5) + 18 + (r - 9 * hh);
      }
#pragma unroll
      for (int m = 0; m < 2; ++m) {
#pragma unroll
        for (int reg = 0; reg < 4; ++reg) {
          const int xo = xb + (m << 4) + (lg << 2) + reg;
          float v = acc[m][nt][reg] + bias;
          if (co >= OFFCH) v = 1.f / (1.f + expf(-v));
          P2[((size_t)n * HW + yout * W_ + xo) * 256 + idx] = (__bf16)v;
        }
      }
    }
  }
}

// ---------------------------------------------------------------------------
// gemm256: D[n][s][co] = sum_c A[n][s][c]*Wb[co][c]
// MODE 0: store bf16 NHWC (vproj -> vtb). MODE 1: store fp32 NCHW (wo -> out).
// ---------------------------------------------------------------------------
template <int MODE>
__global__ __launch_bounds__(256) void gemm256_kernel(
    const __bf16* __restrict__ A, const __bf16* __restrict__ Wb,
    __bf16* __restrict__ out_b, float* __restrict__ out_f)
{
  const int st = blockIdx.x;
  const int bn = blockIdx.y;
  const int n  = blockIdx.z;
  const int s0 = st << 7;
  const int tid = threadIdx.x;

  __shared__ __bf16 Asl[128][40];
  __shared__ __bf16 Bsl[128][40];

  const int lw = tid & 63, wv = tid >> 6;
  const int lr = lw & 15, lg = lw >> 4;
  const int sm_base = wv << 5;

  f32x4 acc[2][8];
#pragma unroll
  for (int m = 0; m < 2; ++m)
#pragma unroll
    for (int nt = 0; nt < 8; ++nt) acc[m][nt] = (f32x4){0.f, 0.f, 0.f, 0.f};

  for (int c0 = 0; c0 < 256; c0 += 32) {
    __syncthreads();
#pragma unroll
    for (int it = 0; it < 2; ++it) {
      int i = tid + (it << 8);
      int cg = i & 3, r = i >> 2;
      *(uint4*)&Asl[r][cg << 3] =
          *(const uint4*)&A[((size_t)n * HW + s0 + r) * 256 + c0 + (cg << 3)];
    }
#pragma unroll
    for (int it = 0; it < 2; ++it) {
      int i = tid + (it << 8);
      int cg = i & 3, r = i >> 2;
      *(uint4*)&Bsl[r][cg << 3] =
          *(const uint4*)&Wb[(size_t)((bn << 7) + r) * 256 + c0 + (cg << 3)];
    }
    __syncthreads();

    bf16x8 a0 = *(const bf16x8*)&Asl[sm_base + lr][lg << 3];
    bf16x8 a1 = *(const bf16x8*)&Asl[sm_base + 16 + lr][lg << 3];
#pragma unroll
    for (int nt = 0; nt < 8; ++nt) {
      bf16x8 b = *(const bf16x8*)&Bsl[(nt << 4) + lr][lg << 3];
      acc[0][nt] = __builtin_amdgcn_mfma_f32_16x16x32_bf16(a0, b, acc[0][nt], 0, 0, 0);
      acc[1][nt] = __builtin_amdgcn_mfma_f32_16x16x32_bf16(a1, b, acc[1][nt], 0, 0, 0);
    }
  }

#pragma unroll
  for (int m = 0; m < 2; ++m) {
#pragma unroll
    for (int nt = 0; nt < 8; ++nt) {
      const int co = (bn << 7) + (nt << 4) + lr;
      if (MODE == 0) {
#pragma unroll
        for (int reg = 0; reg < 4; ++reg) {
          const int sm = sm_base + (m << 4) + (lg << 2) + reg;
          out_b[((size_t)n * HW + s0 + sm) * 256 + co] = (__bf16)acc[m][nt][reg];
        }
      } else {
        const int sm = sm_base + (m << 4) + (lg << 2);
        float4 v4 = make_float4(acc[m][nt][0], acc[m][nt][1],
                                acc[m][nt][2], acc[m][nt][3]);
        *(float4*)&out_f[((size_t)(n * 256 + co)) * HW + s0 + sm] = v4;
      }
    }
  }
}

// ---------------------------------------------------------------------------
// Deformable sampling: 4 lanes per (n,h,s), 8 channels each (bf16x8).
// P params read as 4 vector loads from head-packed P2 (27 contiguous bf16).
// ---------------------------------------------------------------------------
__global__ __launch_bounds__(256) void sample_kernel(
    const __bf16* __restrict__ vtb, const __bf16* __restrict__ P2,
    __bf16* __restrict__ comb)
{
  const int gid = blockIdx.x * 256 + threadIdx.x;
  const int cg  = gid & 3;        // channel oct within head
  const int q   = gid >> 2;       // point index
  const int s = q & (HW - 1);
  const int h = (q >> 12) & (HEADS - 1);
  const int n = q >> 15;
  const int yq = s >> 6, xq = s & 63;

  // packed params: [offx,offy]*9 at 0..17, aw*9 at 18..26 (64B-aligned block)
  const __bf16* prow = P2 + ((size_t)n * HW + s) * 256 + (h << 5);
  bf16x8 p0 = *(const bf16x8*)(prow);       // pairs k=0..3
  bf16x8 p1 = *(const bf16x8*)(prow + 8);   // pairs k=4..7
  bf16x8 p2 = *(const bf16x8*)(prow + 16);  // pair k=8; aw k=0..5
  bf16x4 p3 = *(const bf16x4*)(prow + 24);  // aw k=6..8

  float acc[8];
#pragma unroll
  for (int j = 0; j < 8; ++j) acc[j] = 0.f;

  const __bf16* vbase = vtb + ((size_t)n * HW) * 256 + (h << 5) + (cg << 3);

#pragma unroll
  for (int k = 0; k < K2; ++k) {
    float offx, offy, a;
    if (k < 4)      { offx = (float)p0[2 * k];       offy = (float)p0[2 * k + 1]; }
    else if (k < 8) { offx = (float)p1[2 * (k - 4)]; offy = (float)p1[2 * (k - 4) + 1]; }
    else            { offx = (float)p2[0];           offy = (float)p2[1]; }
    if (k < 6)      a = (float)p2[2 + k];
    else            a = (float)p3[k - 6];

    const float xpf = (float)xq + offx * (63.f / 64.f);
    const float ypf = (float)yq + offy * (63.f / 64.f);
    const float fx0 = floorf(xpf), fy0 = floorf(ypf);
    const int x0 = (int)fx0, y0 = (int)fy0;
    const float wx1 = xpf - fx0, wx0 = 1.f - wx1;
    const float wy1 = ypf - fy0, wy0 = 1.f - wy1;

#pragma unroll
    for (int cy = 0; cy < 2; ++cy) {
      const int yi = y0 + cy;
      if ((unsigned)yi >= (unsigned)H_) continue;
      const float wy = cy ? wy1 : wy0;
#pragma unroll
      for (int cx = 0; cx < 2; ++cx) {
        const int xi = x0 + cx;
        if ((unsigned)xi >= (unsigned)W_) continue;
        const float cw = a * wy * (cx ? wx1 : wx0);
        bf16x8 v = *(const bf16x8*)(vbase + (size_t)(yi * W_ + xi) * 256);
#pragma unroll
        for (int j = 0; j < 8; ++j) acc[j] = fmaf(cw, (float)v[j], acc[j]);
      }
    }
  }

  bf16x8 r;
#pragma unroll
  for (int j = 0; j < 8; ++j) r[j] = (__bf16)acc[j];
  *(bf16x8*)&comb[((size_t)n * HW + s) * 256 + (h << 5) + (cg << 3)] = r;
}

// ---------------------------------------------------------------------------
extern "C" void kernel_launch(void* const* d_in, const int* in_sizes, int n_in,
                              void* d_out, int out_size, void* d_ws,
                              size_t ws_size, hipStream_t stream)
{
  const float* x      = (const float*)d_in[0];
  // d_in[1] = Wq, d_in[2] = Wk : dead code (q,k unused in reference)
  const float* Wv     = (const float*)d_in[3];
  const float* off_w  = (const float*)d_in[4];
  const float* off_b  = (const float*)d_in[5];
  const float* attn_w = (const float*)d_in[6];
  const float* attn_b = (const float*)d_in[7];
  const float* Wo     = (const float*)d_in[8];
  float* out = (float*)d_out;

  __bf16* vtb   = (__bf16*)d_ws;                         // 16.78 MB
  __bf16* xp    = vtb + (size_t)N_ * HW * OUT_;          // 16.78 MB
  __bf16* comb  = xp + (size_t)N_ * HW * C_;             // 16.78 MB
  __bf16* P2    = comb + (size_t)N_ * HW * OUT_;         // 16.78 MB (head-packed)
  __bf16* Wp    = P2 + (size_t)N_ * HW * 256;            //  1.11 MB (240 rows)
  __bf16* Wvb   = Wp + (size_t)WPROWS * KTOT;            //  128 KB
  __bf16* Wob   = Wvb + (size_t)OUT_ * C_;               //  128 KB
  __bf16* zbuf  = Wob + (size_t)OUT_ * OUT_;             //  4 KB zero page
  float*  biasp = (float*)(zbuf + 2048);                 //  896 B

  pack_w_kernel<<<dim3(224), 256, 0, stream>>>(off_w, off_b, attn_w, attn_b,
                                               Wp, biasp, zbuf);
  pack_mat_kernel<<<dim3(256), 256, 0, stream>>>(Wv, Wvb);
  pack_mat_kernel<<<dim3(256), 256, 0, stream>>>(Wo, Wob);
  pack_x_kernel<<<dim3(4, 64, N_), 256, 0, stream>>>(x, xp);
  conv_mfma_kernel<<<dim3(32, 2, N_), 256, 0, stream>>>(xp, Wp, biasp, zbuf, P2);
  gemm256_kernel<0><<<dim3(32, 2, N_), 256, 0, stream>>>(xp, Wvb, vtb, nullptr);
  sample_kernel<<<dim3((N_ * HEADS * HW * 4) / 256), 256, 0, stream>>>(vtb, P2,
                                                                       comb);
  gemm256_kernel<1><<<dim3(32, 2, N_), 256, 0, stream>>>(comb, Wob, nullptr,
                                                         out);
}